// Round 13
// baseline (40.240 us; speedup 1.0000x reference)
//
#include <hip/hip_runtime.h>
#include <math.h>

#define BSZ   65536
#define HALF  32768
#define INP   16
#define HL    10
#define NL    3
#define TT    200
#define NPOP  8600000.0f

#define NCH8  24   // 24 chunks of 8 steps + tail of 7 = 199

__device__ __forceinline__ float fast_tanh(float x) {
    float e = exp2f(x * 2.8853900817779268f);
    return 1.0f - 2.0f * __builtin_amdgcn_rcpf(e + 1.0f);
}

__device__ __forceinline__ float fast_softplus(float x) {
    float t = exp2f(-fabsf(x) * 1.4426950408889634f);
    return fmaxf(x, 0.0f) + 0.6931471805599453f * log2f(1.0f + t);
}

// ---------------- Kernel A: parameter nets, one thread per (sample, net) ----
__global__ __launch_bounds__(256) void mlp_kernel(
    const float* __restrict__ data,
    const float* __restrict__ W0,  const float* __restrict__ b0,
    const float* __restrict__ Wh,  const float* __restrict__ bh,
    const float* __restrict__ Wo,  const float* __restrict__ bo,
    float* __restrict__ vals)         // 3 x B
{
    const int n   = blockIdx.y;
    const int tid = threadIdx.x;

    __shared__ float sW0[HL * INP];
    __shared__ float sb0[HL];
    __shared__ float sWh[NL * HL * HL];
    __shared__ float sbh[NL * HL];
    __shared__ float sWo[HL];
    __shared__ float sbo;

    for (int i = tid; i < HL * INP;      i += 256) sW0[i] = W0[n * HL * INP + i];
    for (int i = tid; i < HL;            i += 256) sb0[i] = b0[n * HL + i];
    for (int i = tid; i < NL * HL * HL;  i += 256) sWh[i] = Wh[n * NL * HL * HL + i];
    for (int i = tid; i < NL * HL;       i += 256) sbh[i] = bh[n * NL * HL + i];
    for (int i = tid; i < HL;            i += 256) sWo[i] = Wo[n * HL + i];
    if (tid == 0) sbo = bo[n];
    __syncthreads();

    const int b = blockIdx.x * 256 + tid;

    float x[INP];
    const float4* xin = reinterpret_cast<const float4*>(data + (size_t)b * INP);
    #pragma unroll
    for (int q = 0; q < INP / 4; ++q) {
        float4 v = xin[q];
        x[q * 4 + 0] = v.x; x[q * 4 + 1] = v.y;
        x[q * 4 + 2] = v.z; x[q * 4 + 3] = v.w;
    }

    float h[HL];
    #pragma unroll
    for (int k = 0; k < HL; ++k) {
        float acc = sb0[k];
        #pragma unroll
        for (int i = 0; i < INP; ++i)
            acc = fmaf(x[i], sW0[k * INP + i], acc);
        h[k] = fast_tanh(acc);
    }
    #pragma unroll
    for (int l = 0; l < NL; ++l) {
        float h2[HL];
        #pragma unroll
        for (int k = 0; k < HL; ++k) {
            float acc = sbh[l * HL + k];
            #pragma unroll
            for (int i = 0; i < HL; ++i)
                acc = fmaf(h[i], sWh[(l * HL + k) * HL + i], acc);
            h2[k] = fast_tanh(acc);
        }
        #pragma unroll
        for (int k = 0; k < HL; ++k) h[k] = h2[k];
    }
    float acc = sbo;
    #pragma unroll
    for (int i = 0; i < HL; ++i)
        acc = fmaf(h[i], sWo[i], acc);

    vals[(size_t)n * BSZ + b] = fast_softplus(acc);
}

// ---------------- Kernel B: RK4, TWO interleaved chains per thread ----------
__global__ __launch_bounds__(64, 1) void sir_kernel(
    const float* __restrict__ vals,   // 3 x B
    const float* __restrict__ times,  // T
    float* __restrict__ out)          // T x B
{
    const int tid = threadIdx.x;
    const int b0i = blockIdx.x * 64 + tid;   // [0, 32768)
    const int b1i = b0i + HALF;

    const float ga = vals[b0i];
    const float gb = vals[b1i];
    const float bea = vals[BSZ + b0i];
    const float beb = vals[BSZ + b1i];
    const float i0a = vals[2 * BSZ + b0i];
    const float i0b = vals[2 * BSZ + b1i];

    __shared__ float sdt[208];        // 52 float4s, zero-padded past 198
    for (int i = tid; i < 208; i += 64)
        sdt[i] = (i < TT - 1) ? (times[i + 1] - times[i]) : 0.0f;
    __syncthreads();

    const float bna = bea * (1.0f / NPOP);
    const float bnb = beb * (1.0f / NPOP);
    float Ia = i0a, Pa = bna * (NPOP - i0a);   // P tracks bn*S
    float Ib = i0b, Pb = bnb * (NPOP - i0b);

    // t = 0 rows via asm store (no compiler vmcnt-guard on I regs)
    {
        unsigned va = (unsigned)b0i * 4u;
        unsigned vb = (unsigned)b1i * 4u;
        asm volatile("global_store_dword %0, %1, %2"
                     :: "v"(va), "v"(Ia), "s"(out) : "memory");
        asm volatile("global_store_dword %0, %1, %2"
                     :: "v"(vb), "v"(Ib), "s"(out) : "memory");
    }

    // two independent depth-14 chains, explicitly interleaved stage by stage
    auto step2 = [&](float dt) {
        const float hdt = 0.5f * dt;
        const float c6  = dt * (1.0f / 6.0f);
        const float hba = bna * hdt,  hbb = bnb * hdt;
        const float dba = bna * dt,   dbb = bnb * dt;
        const float cba = bna * c6,   cbb = bnb * c6;

        float f1a = Pa * Ia;                 float f1b = Pb * Ib;
        float m1a = fmaf(-ga, Ia, f1a);      float m1b = fmaf(-gb, Ib, f1b);
        float aPa = fmaf(-hba, f1a, Pa);     float aPb = fmaf(-hbb, f1b, Pb);
        float aIa = fmaf(hdt, m1a, Ia);      float aIb = fmaf(hdt, m1b, Ib);
        float f2a = aPa * aIa;               float f2b = aPb * aIb;
        float m2a = fmaf(-ga, aIa, f2a);     float m2b = fmaf(-gb, aIb, f2b);
        float bPa = fmaf(-hba, f2a, Pa);     float bPb = fmaf(-hbb, f2b, Pb);
        float bIa = fmaf(hdt, m2a, Ia);      float bIb = fmaf(hdt, m2b, Ib);
        float f3a = bPa * bIa;               float f3b = bPb * bIb;
        float m3a = fmaf(-ga, bIa, f3a);     float m3b = fmaf(-gb, bIb, f3b);
        float cPa = fmaf(-dba, f3a, Pa);     float cPb = fmaf(-dbb, f3b, Pb);
        float cIa = fmaf(dt, m3a, Ia);       float cIb = fmaf(dt, m3b, Ib);
        float f4a = cPa * cIa;               float f4b = cPb * cIb;
        float m4a = fmaf(-ga, cIa, f4a);     float m4b = fmaf(-gb, cIb, f4b);
        float s1a = m1a + m4a;               float s1b = m1b + m4b;
        float s2a = m2a + m3a;               float s2b = m2b + m3b;
        float u1a = f1a + f4a;               float u1b = f1b + f4b;
        float u2a = f2a + f3a;               float u2b = f2b + f3b;
        Ia = fmaf(c6, fmaf(2.0f, s2a, s1a), Ia);
        Ib = fmaf(c6, fmaf(2.0f, s2b, s1b), Ib);
        Pa = fmaf(-cba, fmaf(2.0f, u2a, u1a), Pa);
        Pb = fmaf(-cbb, fmaf(2.0f, u2b, u1b), Pb);
    };

    const float4* sdt4 = reinterpret_cast<const float4*>(sdt);

    float4 da = sdt4[0];
    float4 db4 = sdt4[1];
    float* op = out + BSZ;            // row t = 1

    #pragma unroll 1
    for (int gch = 0; gch < NCH8; ++gch) {
        float4 na = sdt4[2 * gch + 2];
        float4 nb = sdt4[2 * gch + 3];
        __builtin_amdgcn_sched_barrier(0);

        float ja0, ja1, ja2, ja3, ja4, ja5, ja6, ja7;
        float jb0, jb1, jb2, jb3, jb4, jb5, jb6, jb7;
        step2(da.x);  ja0 = Ia; jb0 = Ib; op[b0i          ] = ja0; op[b1i          ] = jb0;
        step2(da.y);  ja1 = Ia; jb1 = Ib; op[b0i + 1 * BSZ] = ja1; op[b1i + 1 * BSZ] = jb1;
        step2(da.z);  ja2 = Ia; jb2 = Ib; op[b0i + 2 * BSZ] = ja2; op[b1i + 2 * BSZ] = jb2;
        step2(da.w);  ja3 = Ia; jb3 = Ib; op[b0i + 3 * BSZ] = ja3; op[b1i + 3 * BSZ] = jb3;
        step2(db4.x); ja4 = Ia; jb4 = Ib; op[b0i + 4 * BSZ] = ja4; op[b1i + 4 * BSZ] = jb4;
        step2(db4.y); ja5 = Ia; jb5 = Ib; op[b0i + 5 * BSZ] = ja5; op[b1i + 5 * BSZ] = jb5;
        step2(db4.z); ja6 = Ia; jb6 = Ib; op[b0i + 6 * BSZ] = ja6; op[b1i + 6 * BSZ] = jb6;
        step2(db4.w); ja7 = Ia; jb7 = Ib; op[b0i + 7 * BSZ] = ja7; op[b1i + 7 * BSZ] = jb7;

        asm volatile("" :: "v"(ja0), "v"(ja1), "v"(ja2), "v"(ja3),
                           "v"(ja4), "v"(ja5), "v"(ja6), "v"(ja7),
                           "v"(jb0), "v"(jb1), "v"(jb2), "v"(jb3),
                           "v"(jb4), "v"(jb5), "v"(jb6), "v"(jb7));

        da = na; db4 = nb;
        op += 8 * BSZ;
    }

    // tail: 7 steps (t = 192..198)
    {
        float d0 = sdt[192], d1 = sdt[193], d2 = sdt[194], d3 = sdt[195];
        float d4 = sdt[196], d5 = sdt[197], d6 = sdt[198];
        float ja0, ja1, ja2, ja3, ja4, ja5, ja6;
        float jb0, jb1, jb2, jb3, jb4, jb5, jb6;
        step2(d0); ja0 = Ia; jb0 = Ib; op[b0i          ] = ja0; op[b1i          ] = jb0;
        step2(d1); ja1 = Ia; jb1 = Ib; op[b0i + 1 * BSZ] = ja1; op[b1i + 1 * BSZ] = jb1;
        step2(d2); ja2 = Ia; jb2 = Ib; op[b0i + 2 * BSZ] = ja2; op[b1i + 2 * BSZ] = jb2;
        step2(d3); ja3 = Ia; jb3 = Ib; op[b0i + 3 * BSZ] = ja3; op[b1i + 3 * BSZ] = jb3;
        step2(d4); ja4 = Ia; jb4 = Ib; op[b0i + 4 * BSZ] = ja4; op[b1i + 4 * BSZ] = jb4;
        step2(d5); ja5 = Ia; jb5 = Ib; op[b0i + 5 * BSZ] = ja5; op[b1i + 5 * BSZ] = jb5;
        step2(d6); ja6 = Ia; jb6 = Ib; op[b0i + 6 * BSZ] = ja6; op[b1i + 6 * BSZ] = jb6;
        asm volatile("" :: "v"(ja0), "v"(ja1), "v"(ja2), "v"(ja3),
                           "v"(ja4), "v"(ja5), "v"(ja6),
                           "v"(jb0), "v"(jb1), "v"(jb2), "v"(jb3),
                           "v"(jb4), "v"(jb5), "v"(jb6));
    }
}

extern "C" void kernel_launch(void* const* d_in, const int* in_sizes, int n_in,
                              void* d_out, int out_size, void* d_ws, size_t ws_size,
                              hipStream_t stream) {
    const float* data  = (const float*)d_in[0];
    const float* times = (const float*)d_in[1];
    const float* W0    = (const float*)d_in[2];
    const float* b0    = (const float*)d_in[3];
    const float* Wh    = (const float*)d_in[4];
    const float* bh    = (const float*)d_in[5];
    const float* Wo    = (const float*)d_in[6];
    const float* bo    = (const float*)d_in[7];
    float* out  = (float*)d_out;
    float* vals = (float*)d_ws;       // 3 * BSZ floats = 768 KB

    dim3 gridA(BSZ / 256, 3);
    mlp_kernel<<<gridA, 256, 0, stream>>>(data, W0, b0, Wh, bh, Wo, bo, vals);
    sir_kernel<<<HALF / 64, 64, 0, stream>>>(vals, times, out);
}

// Round 14
// 30.332 us; speedup vs baseline: 1.3267x; 1.3267x over previous
//
#include <hip/hip_runtime.h>
#include <math.h>

#define BSZ   65536
#define INP   16
#define HL    10
#define NL    3
#define TT    200
#define NPOP  8600000.0f
#define ROWB  262144u            // bytes per t-row of out (BSZ*4)
#define STEPB (64u * ROWB)       // 4-set rotation advance: 64 rows

typedef float f32x4 __attribute__((ext_vector_type(4)));

__device__ __forceinline__ float fast_tanh(float x) {
    float e = exp2f(x * 2.8853900817779268f);
    return 1.0f - 2.0f * __builtin_amdgcn_rcpf(e + 1.0f);
}

__device__ __forceinline__ float fast_softplus(float x) {
    float t = exp2f(-fabsf(x) * 1.4426950408889634f);
    return fmaxf(x, 0.0f) + 0.6931471805599453f * log2f(1.0f + t);
}

// ---------------- Kernel A: parameter nets, one thread per (sample, net) ----
__global__ __launch_bounds__(256) void mlp_kernel(
    const float* __restrict__ data,
    const float* __restrict__ W0,  const float* __restrict__ b0,
    const float* __restrict__ Wh,  const float* __restrict__ bh,
    const float* __restrict__ Wo,  const float* __restrict__ bo,
    float* __restrict__ vals)         // 3 x B
{
    const int n   = blockIdx.y;
    const int tid = threadIdx.x;

    __shared__ float sW0[HL * INP];
    __shared__ float sb0[HL];
    __shared__ float sWh[NL * HL * HL];
    __shared__ float sbh[NL * HL];
    __shared__ float sWo[HL];
    __shared__ float sbo;

    for (int i = tid; i < HL * INP;      i += 256) sW0[i] = W0[n * HL * INP + i];
    for (int i = tid; i < HL;            i += 256) sb0[i] = b0[n * HL + i];
    for (int i = tid; i < NL * HL * HL;  i += 256) sWh[i] = Wh[n * NL * HL * HL + i];
    for (int i = tid; i < NL * HL;       i += 256) sbh[i] = bh[n * NL * HL + i];
    for (int i = tid; i < HL;            i += 256) sWo[i] = Wo[n * HL + i];
    if (tid == 0) sbo = bo[n];
    __syncthreads();

    const int b = blockIdx.x * 256 + tid;

    float x[INP];
    const float4* xin = reinterpret_cast<const float4*>(data + (size_t)b * INP);
    #pragma unroll
    for (int q = 0; q < INP / 4; ++q) {
        float4 v = xin[q];
        x[q * 4 + 0] = v.x; x[q * 4 + 1] = v.y;
        x[q * 4 + 2] = v.z; x[q * 4 + 3] = v.w;
    }

    float h[HL];
    #pragma unroll
    for (int k = 0; k < HL; ++k) {
        float acc = sb0[k];
        #pragma unroll
        for (int i = 0; i < INP; ++i)
            acc = fmaf(x[i], sW0[k * INP + i], acc);
        h[k] = fast_tanh(acc);
    }
    #pragma unroll
    for (int l = 0; l < NL; ++l) {
        float h2[HL];
        #pragma unroll
        for (int k = 0; k < HL; ++k) {
            float acc = sbh[l * HL + k];
            #pragma unroll
            for (int i = 0; i < HL; ++i)
                acc = fmaf(h[i], sWh[(l * HL + k) * HL + i], acc);
            h2[k] = fast_tanh(acc);
        }
        #pragma unroll
        for (int k = 0; k < HL; ++k) h[k] = h2[k];
    }
    float acc = sbo;
    #pragma unroll
    for (int i = 0; i < HL; ++i)
        acc = fmaf(h[i], sWo[i], acc);

    vals[(size_t)n * BSZ + b] = fast_softplus(acc);
}

// ---------------- Kernel B: RK4, 4-set rotated burst store path -------------
#define ST4(VOFF, VAL) \
    asm volatile("global_store_dwordx4 %0, %1, %2" \
                 :: "v"(VOFF), "v"(VAL), "s"(out) : "memory")

__global__ __launch_bounds__(64, 1) void sir_kernel(
    const float* __restrict__ vals,   // 3 x B
    const float* __restrict__ times,  // T
    float* __restrict__ out)          // T x B
{
    const int tid  = threadIdx.x;
    const int b    = blockIdx.x * 64 + tid;
    const int lrow = tid >> 4;        // 0..3
    const int lcol = tid & 15;        // 0..15

    const float g    = vals[b];
    const float beta = vals[BSZ + b];
    const float I0   = vals[2 * BSZ + b];

    __shared__ float sdt[208];        // 52 float4s, zero-padded past 198
    __shared__ float sbuf[16][68];    // I staging, row-padded (bank spread)
    for (int i = tid; i < 208; i += 64)
        sdt[i] = (i < TT - 1) ? (times[i + 1] - times[i]) : 0.0f;
    __syncthreads();

    const float bn = beta * (1.0f / NPOP);
    float I = I0;
    float P = bn * (NPOP - I0);       // P tracks bn*S

    // t = 0 row
    {
        unsigned v0 = (unsigned)b * 4u;
        asm volatile("global_store_dword %0, %1, %2"
                     :: "v"(v0), "v"(I), "s"(out) : "memory");
    }

    auto step = [&](float dt) {
        const float hdt = 0.5f * dt;
        const float hb  = bn * hdt;
        const float db  = bn * dt;
        const float c6  = dt * (1.0f / 6.0f);
        const float cb  = bn * c6;
        float f1 = P * I;
        float m1 = fmaf(-g, I, f1);
        float aP = fmaf(-hb, f1, P);
        float aI = fmaf(hdt, m1, I);
        float f2 = aP * aI;
        float m2 = fmaf(-g, aI, f2);
        float bP = fmaf(-hb, f2, P);
        float bI = fmaf(hdt, m2, I);
        float f3 = bP * bI;
        float m3 = fmaf(-g, bI, f3);
        float cP = fmaf(-db, f3, P);
        float cI = fmaf(dt, m3, I);
        float f4 = cP * cI;
        float m4 = fmaf(-g, cI, f4);
        float s1 = m1 + m4;
        float s2 = m2 + m3;
        float u1 = f1 + f4;
        float u2 = f2 + f3;
        I = fmaf(c6, fmaf(2.0f, s2, s1), I);
        P = fmaf(-cb, fmaf(2.0f, u2, u1), P);
    };

    const float4* sdt4 = reinterpret_cast<const float4*>(sdt);

    // per-(set,q) persistent store addresses; set S used at chunks c≡S (mod 4)
    const unsigned colb = ((unsigned)blockIdx.x * 64u + 4u * (unsigned)lcol) * 4u;
    unsigned vo00, vo01, vo02, vo03, vo10, vo11, vo12, vo13;
    unsigned vo20, vo21, vo22, vo23, vo30, vo31, vo32, vo33;
    #define VINIT(S, Q) (unsigned)(16 * (S) + 4 * (Q) + lrow + 1) * ROWB + colb
    vo00 = VINIT(0,0); vo01 = VINIT(0,1); vo02 = VINIT(0,2); vo03 = VINIT(0,3);
    vo10 = VINIT(1,0); vo11 = VINIT(1,1); vo12 = VINIT(1,2); vo13 = VINIT(1,3);
    vo20 = VINIT(2,0); vo21 = VINIT(2,1); vo22 = VINIT(2,2); vo23 = VINIT(2,3);
    vo30 = VINIT(3,0); vo31 = VINIT(3,1); vo32 = VINIT(3,2); vo33 = VINIT(3,3);

    f32x4 sd00 = 0, sd01 = 0, sd02 = 0, sd03 = 0;
    f32x4 sd10 = 0, sd11 = 0, sd12 = 0, sd13 = 0;
    f32x4 sd20 = 0, sd21 = 0, sd22 = 0, sd23 = 0;
    f32x4 sd30 = 0, sd31 = 0, sd32 = 0, sd33 = 0;

    float4 d0 = sdt4[0], d1 = sdt4[1], d2 = sdt4[2], d3 = sdt4[3];

    // 16 steps with current dts, then reload dts for chunk starting at nextIdx
    auto chunk16 = [&](int nextIdx) {
        step(d0.x); sbuf[ 0][tid] = I;
        step(d0.y); sbuf[ 1][tid] = I;
        step(d0.z); sbuf[ 2][tid] = I;
        step(d0.w); sbuf[ 3][tid] = I;
        step(d1.x); sbuf[ 4][tid] = I;
        step(d1.y); sbuf[ 5][tid] = I;
        step(d1.z); sbuf[ 6][tid] = I;
        step(d1.w); sbuf[ 7][tid] = I;
        step(d2.x); sbuf[ 8][tid] = I;
        step(d2.y); sbuf[ 9][tid] = I;
        step(d2.z); sbuf[10][tid] = I;
        step(d2.w); sbuf[11][tid] = I;
        step(d3.x); sbuf[12][tid] = I;
        step(d3.y); sbuf[13][tid] = I;
        step(d3.z); sbuf[14][tid] = I;
        step(d3.w); sbuf[15][tid] = I;
        d0 = sdt4[nextIdx];     d1 = sdt4[nextIdx + 1];
        d2 = sdt4[nextIdx + 2]; d3 = sdt4[nextIdx + 3];
    };

    #define LDQ(Q) (*(const f32x4*)&sbuf[4 * (Q) + lrow][4 * lcol])

    #define KEEPD() asm volatile("" :: "v"(sd00), "v"(sd01), "v"(sd02), "v"(sd03), \
        "v"(sd10), "v"(sd11), "v"(sd12), "v"(sd13), "v"(sd20), "v"(sd21), \
        "v"(sd22), "v"(sd23), "v"(sd30), "v"(sd31), "v"(sd32), "v"(sd33))
    #define KEEPA() asm volatile("" :: "v"(vo00), "v"(vo01), "v"(vo02), "v"(vo03), \
        "v"(vo10), "v"(vo11), "v"(vo12), "v"(vo13), "v"(vo20), "v"(vo21), \
        "v"(vo22), "v"(vo23), "v"(vo30), "v"(vo31), "v"(vo32), "v"(vo33))

    // WAR guard: set S last used 4 chunks ago; <=12 newer stores may be pending
    #define BURST(S) \
        asm volatile("s_waitcnt vmcnt(12)" ::: "memory"); \
        KEEPD(); KEEPA(); \
        __builtin_amdgcn_sched_barrier(0); \
        sd##S##0 = LDQ(0); sd##S##1 = LDQ(1); \
        sd##S##2 = LDQ(2); sd##S##3 = LDQ(3); \
        ST4(vo##S##0, sd##S##0); ST4(vo##S##1, sd##S##1); \
        ST4(vo##S##2, sd##S##2); ST4(vo##S##3, sd##S##3); \
        vo##S##0 += STEPB; vo##S##1 += STEPB; \
        vo##S##2 += STEPB; vo##S##3 += STEPB; \
        __builtin_amdgcn_sched_barrier(0)

    #pragma unroll 1
    for (int cc = 0; cc < 3; ++cc) {
        chunk16(4 * (4 * cc + 1)); BURST(0);
        chunk16(4 * (4 * cc + 2)); BURST(1);
        chunk16(4 * (4 * cc + 3)); BURST(2);
        chunk16(4 * (4 * cc + 4)); BURST(3);   // cc=2: nextIdx=48 (zero pad)
    }

    // ---------- tail: 7 steps (192..198) -> rows 193..199, set 0 ----------
    step(d0.x); sbuf[0][tid] = I;
    step(d0.y); sbuf[1][tid] = I;
    step(d0.z); sbuf[2][tid] = I;
    step(d0.w); sbuf[3][tid] = I;
    step(d1.x); sbuf[4][tid] = I;
    step(d1.y); sbuf[5][tid] = I;
    step(d1.z); sbuf[6][tid] = I;

    asm volatile("s_waitcnt vmcnt(12)" ::: "memory");
    KEEPD(); KEEPA();
    __builtin_amdgcn_sched_barrier(0);

    // vo00 -> rows 193..196 (all lanes), vo01 -> rows 197..199 (lrow < 3)
    sd00 = LDQ(0);
    ST4(vo00, sd00);
    if (lrow < 3) {
        sd01 = LDQ(1);
        ST4(vo01, sd01);
    }
}

extern "C" void kernel_launch(void* const* d_in, const int* in_sizes, int n_in,
                              void* d_out, int out_size, void* d_ws, size_t ws_size,
                              hipStream_t stream) {
    const float* data  = (const float*)d_in[0];
    const float* times = (const float*)d_in[1];
    const float* W0    = (const float*)d_in[2];
    const float* b0    = (const float*)d_in[3];
    const float* Wh    = (const float*)d_in[4];
    const float* bh    = (const float*)d_in[5];
    const float* Wo    = (const float*)d_in[6];
    const float* bo    = (const float*)d_in[7];
    float* out  = (float*)d_out;
    float* vals = (float*)d_ws;       // 3 * BSZ floats = 768 KB

    dim3 gridA(BSZ / 256, 3);
    mlp_kernel<<<gridA, 256, 0, stream>>>(data, W0, b0, Wh, bh, Wo, bo, vals);
    sir_kernel<<<BSZ / 64, 64, 0, stream>>>(vals, times, out);
}

// Round 16
// 30.280 us; speedup vs baseline: 1.3289x; 1.0017x over previous
//
#include <hip/hip_runtime.h>
#include <math.h>

#define BSZ   65536
#define INP   16
#define HL    10
#define NL    3
#define TT    200
#define NPOP  8600000.0f
#define ROWB  262144u            // bytes per t-row of out (BSZ*4)

typedef float f32x4 __attribute__((ext_vector_type(4)));

__device__ __forceinline__ float fast_tanh(float x) {
    float e = exp2f(x * 2.8853900817779268f);
    return 1.0f - 2.0f * __builtin_amdgcn_rcpf(e + 1.0f);
}

__device__ __forceinline__ float fast_softplus(float x) {
    float t = exp2f(-fabsf(x) * 1.4426950408889634f);
    return fmaxf(x, 0.0f) + 0.6931471805599453f * log2f(1.0f + t);
}

// ---------------- Kernel A: parameter nets, one thread per (sample, net) ----
__global__ __launch_bounds__(256) void mlp_kernel(
    const float* __restrict__ data,
    const float* __restrict__ W0,  const float* __restrict__ b0,
    const float* __restrict__ Wh,  const float* __restrict__ bh,
    const float* __restrict__ Wo,  const float* __restrict__ bo,
    float* __restrict__ vals)         // 3 x B
{
    const int n   = blockIdx.y;
    const int tid = threadIdx.x;

    __shared__ float sW0[HL * INP];
    __shared__ float sb0[HL];
    __shared__ float sWh[NL * HL * HL];
    __shared__ float sbh[NL * HL];
    __shared__ float sWo[HL];
    __shared__ float sbo;

    for (int i = tid; i < HL * INP;      i += 256) sW0[i] = W0[n * HL * INP + i];
    for (int i = tid; i < HL;            i += 256) sb0[i] = b0[n * HL + i];
    for (int i = tid; i < NL * HL * HL;  i += 256) sWh[i] = Wh[n * NL * HL * HL + i];
    for (int i = tid; i < NL * HL;       i += 256) sbh[i] = bh[n * NL * HL + i];
    for (int i = tid; i < HL;            i += 256) sWo[i] = Wo[n * HL + i];
    if (tid == 0) sbo = bo[n];
    __syncthreads();

    const int b = blockIdx.x * 256 + tid;

    float x[INP];
    const float4* xin = reinterpret_cast<const float4*>(data + (size_t)b * INP);
    #pragma unroll
    for (int q = 0; q < INP / 4; ++q) {
        float4 v = xin[q];
        x[q * 4 + 0] = v.x; x[q * 4 + 1] = v.y;
        x[q * 4 + 2] = v.z; x[q * 4 + 3] = v.w;
    }

    float h[HL];
    #pragma unroll
    for (int k = 0; k < HL; ++k) {
        float acc = sb0[k];
        #pragma unroll
        for (int i = 0; i < INP; ++i)
            acc = fmaf(x[i], sW0[k * INP + i], acc);
        h[k] = fast_tanh(acc);
    }
    #pragma unroll
    for (int l = 0; l < NL; ++l) {
        float h2[HL];
        #pragma unroll
        for (int k = 0; k < HL; ++k) {
            float acc = sbh[l * HL + k];
            #pragma unroll
            for (int i = 0; i < HL; ++i)
                acc = fmaf(h[i], sWh[(l * HL + k) * HL + i], acc);
            h2[k] = fast_tanh(acc);
        }
        #pragma unroll
        for (int k = 0; k < HL; ++k) h[k] = h2[k];
    }
    float acc = sbo;
    #pragma unroll
    for (int i = 0; i < HL; ++i)
        acc = fmaf(h[i], sWo[i], acc);

    vals[(size_t)n * BSZ + b] = fast_softplus(acc);
}

// ---------------- Kernel B: producer/consumer wave specialization -----------
// wave 0: pure-ALU RK4 chains (no global mem ops, no vmcnt waits)
// wave 1: drains LDS slabs to HBM (eats all store latency in its slack)
#define ST4(VOFF, VAL) \
    asm volatile("global_store_dwordx4 %0, %1, %2" \
                 :: "v"(VOFF), "v"(VAL), "s"(out) : "memory")

__global__ __launch_bounds__(128, 1) void sir_kernel(
    const float* __restrict__ vals,   // 3 x B
    const float* __restrict__ times,  // T
    float* __restrict__ out)          // T x B
{
    const int tid = threadIdx.x;
    const int w   = tid >> 6;         // 0 = compute wave, 1 = store wave
    const int l   = tid & 63;
    const int b0  = blockIdx.x * 64;
    const int b   = b0 + l;

    __shared__ float sdt[208];           // dt table, zero-padded past 198
    __shared__ float slab[2][16][68];    // I staging, double-buffered, padded

    for (int i = tid; i < 208; i += 128)
        sdt[i] = (i < TT - 1) ? (times[i + 1] - times[i]) : 0.0f;
    __syncthreads();                     // pre-loop sync (both waves)

    const float4* sdt4 = reinterpret_cast<const float4*>(sdt);

    if (w == 0) {
        // ================= COMPUTE WAVE =================
        const float g    = vals[b];
        const float beta = vals[BSZ + b];
        const float I0v  = vals[2 * BSZ + b];
        const float bn = beta * (1.0f / NPOP);
        float I = I0v;
        float P = bn * (NPOP - I0v);     // P tracks bn*S

        auto step = [&](float dt) {
            const float hdt = 0.5f * dt;
            const float hb  = bn * hdt;
            const float db  = bn * dt;
            const float c6  = dt * (1.0f / 6.0f);
            const float cb  = bn * c6;
            float f1 = P * I;
            float m1 = fmaf(-g, I, f1);
            float aP = fmaf(-hb, f1, P);
            float aI = fmaf(hdt, m1, I);
            float f2 = aP * aI;
            float m2 = fmaf(-g, aI, f2);
            float bP = fmaf(-hb, f2, P);
            float bI = fmaf(hdt, m2, I);
            float f3 = bP * bI;
            float m3 = fmaf(-g, bI, f3);
            float cP = fmaf(-db, f3, P);
            float cI = fmaf(dt, m3, I);
            float f4 = cP * cI;
            float m4 = fmaf(-g, cI, f4);
            float s1 = m1 + m4;
            float s2 = m2 + m3;
            float u1 = f1 + f4;
            float u2 = f2 + f3;
            I = fmaf(c6, fmaf(2.0f, s2, s1), I);
            P = fmaf(-cb, fmaf(2.0f, u2, u1), P);
        };

        float4 d0 = sdt4[0], d1 = sdt4[1], d2 = sdt4[2], d3 = sdt4[3];

        // one 16-step chunk into slab[BUF]; then reload dts from NEXT (<=48)
        #define CHUNK(BUF, NEXT) do {                                        \
            float j0, j1, j2, j3, j4, j5, j6, j7;                            \
            float j8, j9, j10, j11, j12, j13, j14, j15;                      \
            step(d0.x); j0  = I;  step(d0.y); j1  = I;                       \
            step(d0.z); j2  = I;  step(d0.w); j3  = I;                       \
            step(d1.x); j4  = I;  step(d1.y); j5  = I;                       \
            step(d1.z); j6  = I;  step(d1.w); j7  = I;                       \
            step(d2.x); j8  = I;  step(d2.y); j9  = I;                       \
            step(d2.z); j10 = I;  step(d2.w); j11 = I;                       \
            step(d3.x); j12 = I;  step(d3.y); j13 = I;                       \
            step(d3.z); j14 = I;  step(d3.w); j15 = I;                       \
            slab[BUF][ 0][l] = j0;  slab[BUF][ 1][l] = j1;                   \
            slab[BUF][ 2][l] = j2;  slab[BUF][ 3][l] = j3;                   \
            slab[BUF][ 4][l] = j4;  slab[BUF][ 5][l] = j5;                   \
            slab[BUF][ 6][l] = j6;  slab[BUF][ 7][l] = j7;                   \
            slab[BUF][ 8][l] = j8;  slab[BUF][ 9][l] = j9;                   \
            slab[BUF][10][l] = j10; slab[BUF][11][l] = j11;                  \
            slab[BUF][12][l] = j12; slab[BUF][13][l] = j13;                  \
            slab[BUF][14][l] = j14; slab[BUF][15][l] = j15;                  \
            d0 = sdt4[(NEXT)];     d1 = sdt4[(NEXT) + 1];                    \
            d2 = sdt4[(NEXT) + 2]; d3 = sdt4[(NEXT) + 3];                    \
            asm volatile("s_waitcnt lgkmcnt(0)" ::: "memory");               \
            __builtin_amdgcn_sched_barrier(0);                               \
            __builtin_amdgcn_s_barrier();                                    \
            __builtin_amdgcn_sched_barrier(0);                               \
        } while (0)

        #pragma unroll 1
        for (int cc = 0; cc < 5; ++cc) {
            CHUNK(0, 8 * cc + 8);        // chunks 0,2,4,6,8
            CHUNK(1, 8 * cc + 12);       // chunks 1,3,5,7,9 (max NEXT=44)
        }
        CHUNK(0, 48);                    // chunk 10
        CHUNK(1, 48);                    // chunk 11 (re-reads 48..51, in-bounds)

        // tail chunk (c = 12, buf 0): 7 steps, rows 193..199
        {
            float j0, j1, j2, j3, j4, j5, j6;
            step(d0.x); j0 = I;  step(d0.y); j1 = I;
            step(d0.z); j2 = I;  step(d0.w); j3 = I;
            step(d1.x); j4 = I;  step(d1.y); j5 = I;
            step(d1.z); j6 = I;
            slab[0][0][l] = j0; slab[0][1][l] = j1;
            slab[0][2][l] = j2; slab[0][3][l] = j3;
            slab[0][4][l] = j4; slab[0][5][l] = j5;
            slab[0][6][l] = j6;
            asm volatile("s_waitcnt lgkmcnt(0)" ::: "memory");
            __builtin_amdgcn_sched_barrier(0);
            __builtin_amdgcn_s_barrier();
        }
    } else {
        // ================= STORE WAVE =================
        const int lr = l >> 4;           // 0..3
        const int lc = l & 15;           // 0..15

        // row t = 0 directly from vals (I0 = vals row 2)
        out[b] = vals[2 * BSZ + b];

        const unsigned cb = ((unsigned)b0 + 4u * (unsigned)lc) * 4u;
        unsigned vo0 = (unsigned)( 1 + lr) * ROWB + cb;
        unsigned vo1 = (unsigned)( 5 + lr) * ROWB + cb;
        unsigned vo2 = (unsigned)( 9 + lr) * ROWB + cb;
        unsigned vo3 = (unsigned)(13 + lr) * ROWB + cb;

        #pragma unroll 1
        for (int k = 0; k < 12; ++k) {
            __builtin_amdgcn_s_barrier();          // slab[k&1] ready
            __builtin_amdgcn_sched_barrier(0);
            // WAR guard for the v0..v3 regs feeding last iteration's stores;
            // runs in THIS wave's slack — compute wave never waits on it
            asm volatile("s_waitcnt vmcnt(0)" ::: "memory");
            const float* sb = &slab[k & 1][0][0];
            f32x4 v0 = *(const f32x4*)(sb + (lr     ) * 68 + 4 * lc);
            f32x4 v1 = *(const f32x4*)(sb + (lr +  4) * 68 + 4 * lc);
            f32x4 v2 = *(const f32x4*)(sb + (lr +  8) * 68 + 4 * lc);
            f32x4 v3 = *(const f32x4*)(sb + (lr + 12) * 68 + 4 * lc);
            ST4(vo0, v0); ST4(vo1, v1); ST4(vo2, v2); ST4(vo3, v3);
            vo0 += 16u * ROWB; vo1 += 16u * ROWB;
            vo2 += 16u * ROWB; vo3 += 16u * ROWB;
        }
        // tail (chunk 12, buf 0): rows 193..199 = slab rows 0..6
        __builtin_amdgcn_s_barrier();
        __builtin_amdgcn_sched_barrier(0);
        asm volatile("s_waitcnt vmcnt(0)" ::: "memory");
        {
            const float* sb = &slab[0][0][0];
            f32x4 v0 = *(const f32x4*)(sb + (lr    ) * 68 + 4 * lc);
            ST4(vo0, v0);                                  // rows 193..196
            if (lr < 3) {
                f32x4 v1 = *(const f32x4*)(sb + (lr + 4) * 68 + 4 * lc);
                ST4(vo1, v1);                              // rows 197..199
            }
        }
    }
}

extern "C" void kernel_launch(void* const* d_in, const int* in_sizes, int n_in,
                              void* d_out, int out_size, void* d_ws, size_t ws_size,
                              hipStream_t stream) {
    const float* data  = (const float*)d_in[0];
    const float* times = (const float*)d_in[1];
    const float* W0    = (const float*)d_in[2];
    const float* b0    = (const float*)d_in[3];
    const float* Wh    = (const float*)d_in[4];
    const float* bh    = (const float*)d_in[5];
    const float* Wo    = (const float*)d_in[6];
    const float* bo    = (const float*)d_in[7];
    float* out  = (float*)d_out;
    float* vals = (float*)d_ws;       // 3 * BSZ floats = 768 KB

    dim3 gridA(BSZ / 256, 3);
    mlp_kernel<<<gridA, 256, 0, stream>>>(data, W0, b0, Wh, bh, Wo, bo, vals);
    sir_kernel<<<BSZ / 64, 128, 0, stream>>>(vals, times, out);
}